// Round 2
// baseline (623.426 us; speedup 1.0000x reference)
//
#include <hip/hip_runtime.h>
#include <math.h>

// ForwardWarpStereo: horizontal-only forward splat with disparity weights.
// im:   [B=4, C=3, H=1080, W=1920] f32
// disp: [B, 1, H, W] f32 in [0, 40)
// out:  res [B,C,H,W] then occlu [B,1,H,W], concatenated flat.
//
// flow = (-disp, 0)  =>  splat targets stay in the source row, x0 = floor(x-d)
// in [x-40, x]. Row H-1 never splats (y1 = H > H-1 fails validity).
// disp.min() cancels in both outputs (res is a weighted-average ratio; occlu
// is unweighted), so no global-min pass is needed.

constexpr int Bn = 4, Cn = 3, Hn = 1080, Wn = 1920;
constexpr int TILE = 512;          // output pixels per block
constexpr int HALO = 41;           // sources [X-1, X+TILE+39]
constexpr int NSRC = TILE + HALO;  // 553
constexpr float K_LOG2 = 0.49978214f;  // log2(1.414)
constexpr float EPSV = 1e-6f;

__global__ __launch_bounds__(256)
void fwarp_stereo_kernel(const float* __restrict__ im,
                         const float* __restrict__ disp,
                         float* __restrict__ out) {
  // 5 accumulators per output pixel: R, G, B, weight-mask, count
  __shared__ float acc[5][TILE];
  float* accf = &acc[0][0];
  for (int i = threadIdx.x; i < 5 * TILE; i += 256) accf[i] = 0.0f;
  __syncthreads();

  const int row = blockIdx.y;        // b*H + y
  const int b = row / Hn;
  const int y = row - b * Hn;
  const int X = blockIdx.x * TILE;   // first output x owned by this block
  const size_t HW = (size_t)Hn * Wn;

  const float* dRow  = disp + (size_t)row * Wn;
  const float* imRow = im + (size_t)b * Cn * HW + (size_t)y * Wn;

  if (y < Hn - 1) {  // row H-1 is invalid in the reference (y1 > H-1)
    for (int s = threadIdx.x; s < NSRC; s += 256) {
      const int x = X - 1 + s;
      if (x < 0 || x >= Wn) continue;
      const float d   = dRow[x];
      const float xs  = (float)x - d;
      const float x0f = floorf(xs);
      const int   x0  = (int)x0f;
      if (x0 < 0 || x0 > Wn - 2) continue;  // need x0>=0 && x0+1<=W-1
      const float wx1 = xs - x0f;
      const float wx0 = 1.0f - wx1;
      const float w   = exp2f(K_LOG2 * d);  // 1.414^d
      const float r  = imRow[x];
      const float g  = imRow[HW + x];
      const float bl = imRow[2 * HW + x];
      const float wr = r * w, wg = g * w, wb = bl * w;

      const int t0 = x0 - X;
      if (t0 >= 0 && t0 < TILE) {
        atomicAdd(&acc[0][t0], wr * wx0);
        atomicAdd(&acc[1][t0], wg * wx0);
        atomicAdd(&acc[2][t0], wb * wx0);
        atomicAdd(&acc[3][t0], w * wx0);
        atomicAdd(&acc[4][t0], wx0);
      }
      const int t1 = t0 + 1;
      if (t1 >= 0 && t1 < TILE) {
        atomicAdd(&acc[0][t1], wr * wx1);
        atomicAdd(&acc[1][t1], wg * wx1);
        atomicAdd(&acc[2][t1], wb * wx1);
        atomicAdd(&acc[3][t1], w * wx1);
        atomicAdd(&acc[4][t1], wx1);
      }
    }
  }
  __syncthreads();

  float* outRes = out + (size_t)b * Cn * HW + (size_t)y * Wn;
  float* outOcc = out + (size_t)Bn * Cn * HW + (size_t)row * Wn;
  for (int i = threadIdx.x; i < TILE; i += 256) {
    const int xo = X + i;
    if (xo >= Wn) continue;
    const float m   = fmaxf(acc[3][i], EPSV);
    const float inv = 1.0f / m;
    outRes[xo]          = acc[0][i] * inv;
    outRes[HW + xo]     = acc[1][i] * inv;
    outRes[2 * HW + xo] = acc[2][i] * inv;
    outOcc[xo]          = 1.0f - fminf(acc[4][i], 1.0f);
  }
}

extern "C" void kernel_launch(void* const* d_in, const int* in_sizes, int n_in,
                              void* d_out, int out_size, void* d_ws, size_t ws_size,
                              hipStream_t stream) {
  const float* im   = (const float*)d_in[0];
  const float* disp = (const float*)d_in[1];
  float* out = (float*)d_out;
  dim3 grid((Wn + TILE - 1) / TILE, Bn * Hn);  // (4, 4320)
  fwarp_stereo_kernel<<<grid, dim3(256), 0, stream>>>(im, disp, out);
}

// Round 3
// 268.997 us; speedup vs baseline: 2.3176x; 2.3176x over previous
//
#include <hip/hip_runtime.h>
#include <math.h>

// ForwardWarpStereo — gather formulation (no atomics).
// flow = (-disp, 0), disp in [0,40): output t receives only from sources
// x in [t-1, t+47]; bilinear splat weight to t == max(0, 1-|xs-t|) (triangle),
// valid iff floor(xs) in [0, W-2]. disp.min() cancels (res is a ratio; occlu
// unweighted). Row H-1 never splats => res=0, occlu=1.
//
// Block = one image row (grid 4*1080). Stage {xs,w} and {r,g,b} in LDS,
// transposed [s&7][s>>3] so unrolled candidate j reads row-const/col=tid+const
// (conflict-free, immediate ds offsets). Each thread owns K=8 outputs in regs.

constexpr int Bn = 4, Cn = 3, Hn = 1080, Wn = 1920;
constexpr int NT = 256;
constexpr int K = 8;
constexpr int NACT = Wn / K;       // 240 gather threads
constexpr int RS = 247;            // padded col stride; cols used 0..246
constexpr float K_LOG2 = 0.49978214f;  // log2(1.414)
constexpr float EPSV = 1e-6f;

__global__ __launch_bounds__(NT)
void fwarp_gather(const float* __restrict__ im,
                  const float* __restrict__ disp,
                  float* __restrict__ out) {
  __shared__ float2 As[8 * RS];   // {xs (or -1e9 sentinel), w}
  __shared__ float4 Cs[8 * RS];   // {r, g, b, 0}

  const int tid = threadIdx.x;
  const int row = blockIdx.x;          // b*H + y
  const int b = row / Hn;
  const int y = row - b * Hn;
  const size_t HW = (size_t)Hn * Wn;
  const float* dR = disp + (size_t)row * Wn;
  const float* iR = im + (size_t)b * Cn * HW + (size_t)y * Wn;
  const bool live = (y < Hn - 1);

  if (live) {
    // real sources: col' = (s>>3) + 1, row' = s&7
    #pragma unroll
    for (int it = 0; it < 8; ++it) {
      int s = tid + it * NT;
      if (s < Wn) {
        float d  = dR[s];
        float xs = (float)s - d;
        float mf = floorf(xs);
        float w  = exp2f(K_LOG2 * d);          // 1.414^d
        bool valid = (mf >= 0.0f) && (mf <= (float)(Wn - 2));
        int idx = (s & 7) * RS + (s >> 3) + 1;
        As[idx] = make_float2(valid ? xs : -1.0e9f, w);
        Cs[idx] = make_float4(iR[s], iR[HW + s], iR[2 * HW + s], 0.0f);
      }
    }
    // sentinels: s = -1 and s in [Wn, Wn+47]
    if (tid < 49) {
      int s = (tid == 48) ? -1 : (Wn + tid);
      int idx = (s & 7) * RS + (s >> 3) + 1;   // s=-1 -> row 7, col 0
      As[idx] = make_float2(-1.0e9f, 0.0f);
      Cs[idx] = make_float4(0.0f, 0.0f, 0.0f, 0.0f);
    }
  }
  __syncthreads();

  float aR[K], aG[K], aB[K], aM[K], aC[K];
  #pragma unroll
  for (int o = 0; o < K; ++o) { aR[o] = aG[o] = aB[o] = aM[o] = aC[o] = 0.0f; }

  const int tb = tid * K;
  const float tbf = (float)tb;

  auto cand = [&](int j) {
    // s = tb - 1 + j ; tb % 8 == 0 so s&7 = (j-1)&7, s>>3 = tid + ((j-1)>>3)
    const int r8 = (j - 1) & 7;
    const int cl = tid + ((j - 1) >> 3) + 1;   // col' (sentinel-shifted)
    float2 a = As[r8 * RS + cl];
    float4 c = Cs[r8 * RS + cl];
    float xr = a.x - tbf;
    float w  = a.y;
    #pragma unroll
    for (int o = 0; o < K; ++o) {
      float u  = xr - (float)o;
      float wt = fmaxf(1.0f - fabsf(u), 0.0f);  // triangle splat weight
      float f  = wt * w;
      aR[o] = fmaf(f, c.x, aR[o]);
      aG[o] = fmaf(f, c.y, aG[o]);
      aB[o] = fmaf(f, c.z, aB[o]);
      aM[o] += f;
      aC[o] += wt;
    }
  };

  if (live && tid < NACT) {
    #pragma unroll 16
    for (int j = 0; j < 48; ++j) cand(j);
    cand(48);
  }

  if (tid < NACT) {
    float* oRes = out + (size_t)b * Cn * HW + (size_t)y * Wn + tb;
    float* oOcc = out + (size_t)Bn * Cn * HW + (size_t)row * Wn + tb;
    float rv[K], gv[K], bv[K], ov[K];
    #pragma unroll
    for (int o = 0; o < K; ++o) {
      float m   = fmaxf(aM[o], EPSV);
      float inv = 1.0f / m;
      rv[o] = aR[o] * inv;
      gv[o] = aG[o] * inv;
      bv[o] = aB[o] * inv;
      ov[o] = 1.0f - fminf(aC[o], 1.0f);
    }
    float4* p;
    p = (float4*)oRes;
    p[0] = make_float4(rv[0], rv[1], rv[2], rv[3]);
    p[1] = make_float4(rv[4], rv[5], rv[6], rv[7]);
    p = (float4*)(oRes + HW);
    p[0] = make_float4(gv[0], gv[1], gv[2], gv[3]);
    p[1] = make_float4(gv[4], gv[5], gv[6], gv[7]);
    p = (float4*)(oRes + 2 * HW);
    p[0] = make_float4(bv[0], bv[1], bv[2], bv[3]);
    p[1] = make_float4(bv[4], bv[5], bv[6], bv[7]);
    p = (float4*)oOcc;
    p[0] = make_float4(ov[0], ov[1], ov[2], ov[3]);
    p[1] = make_float4(ov[4], ov[5], ov[6], ov[7]);
  }
}

extern "C" void kernel_launch(void* const* d_in, const int* in_sizes, int n_in,
                              void* d_out, int out_size, void* d_ws, size_t ws_size,
                              hipStream_t stream) {
  const float* im   = (const float*)d_in[0];
  const float* disp = (const float*)d_in[1];
  float* out = (float*)d_out;
  fwarp_gather<<<dim3(Bn * Hn), dim3(NT), 0, stream>>>(im, disp, out);
}